// Round 7
// baseline (400.417 us; speedup 1.0000x reference)
//
#include <hip/hip_runtime.h>
#include <hip/hip_cooperative_groups.h>
#include <math.h>

namespace cg = cooperative_groups;

// ---------------------------------------------------------------------------
// TropicalMLP, R15: ONE cooperative kernel (was 6 dispatches in R13/R14).
// Cross-round accounting showed ~8us per dispatch boundary: R13/R14's seven
// dispatches carried ~55us of boundary overhead vs ~15us of actual compute.
// All phases now run inside one hipLaunchCooperativeKernel with grid.sync()
// between them (device-scope fence -> correct across XCD L2s, guide G16):
//   P0 prep (exp W1/W2/W3 + 4*exp(x) -> fp8 MFMA-fragment order, grid-stride)
//   P1 gemm L1 (2048 waves, 16x16 tiles)   P2 LN1 (1024 waves, 1 row/wave)
//   P3 gemm L2                             P4 LN2
//   P5 gemm L3 (1024 waves) -> out
// Geometry/math verbatim R14 (passed, absmax 0.125): layer1 A=4*exp(x)
// (+ln4 cancels in LN1 median); layers2/3 A=64*exp(y-cm) (+ln64-cm cancels
// in LN2 median / subtracted in final epilogue). B=exp(w) in [0.6,1.6].
// Grid 512x256 = 2 blocks/CU co-resident; no LDS; VGPR ~75 (cap 256,2).
// ---------------------------------------------------------------------------

typedef float v4f __attribute__((ext_vector_type(4)));

#define LN64f 4.1588830833596715f  // ln(64)

__device__ __forceinline__ int pk4_fp8(float a, float b, float c, float d) {
    int p = __builtin_amdgcn_cvt_pk_fp8_f32(a, b, 0, 0);      // bytes 0,1
    p = __builtin_amdgcn_cvt_pk_fp8_f32(c, d, p, 1);          // bytes 2,3
    return p;
}

// One wave: C[16 rows x 16 cols] over K=512, fp8 MFMA, rolling depth-8 B
// prefetch. ap = Af + m*8192 + lane*8, bp = Bf + n16*8192 + lane*8.
__device__ __forceinline__ v4f gemm_k512_1(const uint8_t* __restrict__ ap,
                                           const uint8_t* __restrict__ bp) {
    long areg[16];
    long bb[8];
#pragma unroll
    for (int t = 0; t < 16; ++t)
        areg[t] = *reinterpret_cast<const long*>(ap + t * 512);
#pragma unroll
    for (int p = 0; p < 8; ++p)
        bb[p] = *reinterpret_cast<const long*>(bp + p * 512);
    v4f acc = (v4f){0.f, 0.f, 0.f, 0.f};
#pragma unroll
    for (int t = 0; t < 16; ++t) {
        long a = areg[t];
        long bcur = bb[t & 7];
        if (t < 8)
            bb[t & 7] = *reinterpret_cast<const long*>(bp + (t + 8) * 512);
        acc = __builtin_amdgcn_mfma_f32_16x16x32_fp8_fp8(a, bcur, acc, 0, 0, 0);
    }
    return acc;
}

// Tropical-LN body for one row (one wave, 8 elem/lane, zero barriers):
// exact order stats via in-register bitonic (compact runtime loops); relu;
// subtract rowmax; A = 64*exp(y-cm) scattered fp8 into next layer's
// fragment order. Verbatim R14 ln_rows internals.
__device__ __forceinline__ void ln_one_row(int rho, int lane,
                                           const float* __restrict__ h,
                                           const float* __restrict__ lw,
                                           const float* __restrict__ lb,
                                           uint8_t* __restrict__ Aout,
                                           float* __restrict__ crow) {
    const float4* lw4 = reinterpret_cast<const float4*>(lw + lane * 8);
    const float4* lb4 = reinterpret_cast<const float4*>(lb + lane * 8);
    float4 wa = lw4[0], wb = lw4[1], ba = lb4[0], bbv = lb4[1];

    float hv[8], v[8];
    {
        const float* hp = h + rho * 512 + lane * 8;
        float4 a = *reinterpret_cast<const float4*>(hp);
        float4 b = *reinterpret_cast<const float4*>(hp + 4);
        hv[0] = a.x; hv[1] = a.y; hv[2] = a.z; hv[3] = a.w;
        hv[4] = b.x; hv[5] = b.y; hv[6] = b.z; hv[7] = b.w;
#pragma unroll
        for (int j = 0; j < 8; ++j) v[j] = hv[j];
    }
    // Bitonic sort of 512 values, element e = lane*8 + j, ascending.
#pragma clang loop unroll(disable)
    for (int k = 2; k <= 512; k <<= 1) {
#pragma clang loop unroll(disable)
        for (int jj = 256; jj > 0; jj >>= 1) {
            if (jj >= k) continue;
            if (jj >= 8) {
                int lm = jj >> 3;
#pragma unroll
                for (int j = 0; j < 8; ++j) {
                    float pv = __shfl_xor(v[j], lm);
                    bool up = ((((lane << 3) | j) & k) == 0);
                    bool low = ((lane & lm) == 0);
                    v[j] = (up == low) ? fminf(v[j], pv) : fmaxf(v[j], pv);
                }
            } else if (jj == 4) {
#pragma unroll
                for (int j = 0; j < 4; ++j) {
                    bool up = ((((lane << 3) | j) & k) == 0);
                    float a = v[j], c = v[j + 4];
                    float lo = fminf(a, c), hi = fmaxf(a, c);
                    v[j] = up ? lo : hi;
                    v[j + 4] = up ? hi : lo;
                }
            } else if (jj == 2) {
#pragma unroll
                for (int jb = 0; jb < 8; jb += 4)
#pragma unroll
                    for (int j0 = 0; j0 < 2; ++j0) {
                        int j = jb + j0;
                        bool up = ((((lane << 3) | j) & k) == 0);
                        float a = v[j], c = v[j + 2];
                        float lo = fminf(a, c), hi = fmaxf(a, c);
                        v[j] = up ? lo : hi;
                        v[j + 2] = up ? hi : lo;
                    }
            } else {
#pragma unroll
                for (int j = 0; j < 8; j += 2) {
                    bool up = ((((lane << 3) | j) & k) == 0);
                    float a = v[j], c = v[j + 1];
                    float lo = fminf(a, c), hi = fmaxf(a, c);
                    v[j] = up ? lo : hi;
                    v[j + 1] = up ? hi : lo;
                }
            }
        }
    }
    float s127 = __shfl(v[7], 15);
    float s128 = __shfl(v[0], 16);
    float med  = __shfl(v[7], 31);
    float s383 = __shfl(v[7], 47);
    float s384 = __shfl(v[0], 48);
    float q25 = s127 + 0.75f * (s128 - s127);
    float q75 = s383 + 0.25f * (s384 - s383);
    float inv = 1.0f / fmaxf(q75 - q25, 1e-6f);

    float y[8], cm = 0.0f;                      // y >= 0 after relu
    {
        float lwv[8] = {wa.x, wa.y, wa.z, wa.w, wb.x, wb.y, wb.z, wb.w};
        float lbv[8] = {ba.x, ba.y, ba.z, ba.w, bbv.x, bbv.y, bbv.z, bbv.w};
#pragma unroll
        for (int j = 0; j < 8; ++j) {
            y[j] = fmaxf((hv[j] - med) * inv * lwv[j] + lbv[j], 0.0f);
            cm = fmaxf(cm, y[j]);
        }
    }
#pragma unroll
    for (int s = 32; s > 0; s >>= 1) cm = fmaxf(cm, __shfl_xor(cm, s));
    {
        float e[8];
#pragma unroll
        for (int j = 0; j < 8; ++j) e[j] = 64.0f * __expf(y[j] - cm);
        int2 o;
        o.x = pk4_fp8(e[0], e[1], e[2], e[3]);
        o.y = pk4_fp8(e[4], e[5], e[6], e[7]);
        // fragment scatter: element e=lane*8+j of row rho -> k-step t=lane>>2,
        // frag lane l' = (lane&3)*16 + (rho&15)
        uint8_t* dst = Aout + ((rho >> 4) * 16 + (lane >> 2)) * 512
                            + ((lane & 3) * 16 + (rho & 15)) * 8;
        *reinterpret_cast<int2*>(dst) = o;
    }
    if (lane == 0) crow[rho] = cm;
}

__global__ __launch_bounds__(256, 2) void trop_all(
    const float* __restrict__ x,
    const float* __restrict__ w1, const float* __restrict__ b1,
    const float* __restrict__ ln1w, const float* __restrict__ ln1b,
    const float* __restrict__ w2, const float* __restrict__ b2,
    const float* __restrict__ ln2w, const float* __restrict__ ln2b,
    const float* __restrict__ w3, const float* __restrict__ b3,
    uint8_t* __restrict__ Ew, uint8_t* __restrict__ A1,
    uint8_t* __restrict__ A2, uint8_t* __restrict__ A3,
    float* __restrict__ h, float* __restrict__ crow,
    float* __restrict__ out)
{
    cg::grid_group grid = cg::this_grid();
    const int tid = threadIdx.x, blk = blockIdx.x;
    const int lane = tid & 63, w = tid >> 6;
    const int r = lane & 15, q = lane >> 4;

    // ---- P0: prep. fp8 exp, MFMA-fragment order. 147456 items, grid-stride.
    // u: lane l=q*16+r, k-step t, 16-col tile S:
    //   dst[(tile*16+t)*512 + l*8 + j] = fp8(sc*exp(M[tile*16+r][t*32+q*8+j]))
    // S: 0..31 w1 | 32..63 w2 | 64..79 w3 | 80..143 x (sc=4).
    for (int u = blk * 256 + tid; u < 147456; u += 131072) {
        int ul = u & 63, t = (u >> 6) & 15, S = u >> 10;
        int ur = ul & 15, uq = ul >> 4;
        const float* m; int tile; uint8_t* dst; float sc;
        if (S < 32)      { m = w1; tile = S;      dst = Ew;          sc = 1.0f; }
        else if (S < 64) { m = w2; tile = S - 32; dst = Ew + 262144; sc = 1.0f; }
        else if (S < 80) { m = w3; tile = S - 64; dst = Ew + 524288; sc = 1.0f; }
        else             { m = x;  tile = S - 80; dst = A1;          sc = 4.0f; }
        const float* src = m + (tile * 16 + ur) * 512 + t * 32 + uq * 8;
        float4 a = *reinterpret_cast<const float4*>(src);
        float4 b = *reinterpret_cast<const float4*>(src + 4);
        int2 o;
        o.x = pk4_fp8(sc * __expf(a.x), sc * __expf(a.y),
                      sc * __expf(a.z), sc * __expf(a.w));
        o.y = pk4_fp8(sc * __expf(b.x), sc * __expf(b.y),
                      sc * __expf(b.z), sc * __expf(b.w));
        *reinterpret_cast<int2*>(dst + (tile * 16 + t) * 512 + ul * 8) = o;
    }
    grid.sync();

    // ---- P1: gemm L1. Wave W = blk*4+w (0..2047): m=W>>5, n16=W&31.
    {
        int W = blk * 4 + w;
        int m = W >> 5, n16 = W & 31;
        v4f acc = gemm_k512_1(A1 + m * 8192 + lane * 8,
                              Ew + n16 * 8192 + lane * 8);
        int col = n16 * 16 + r;
        float bv = b1[col];
#pragma unroll
        for (int tt = 0; tt < 4; ++tt)
            h[(m * 16 + q * 4 + tt) * 512 + col] = __logf(acc[tt]) + bv;
    }
    grid.sync();

    // ---- P2: LN1. Waves 0,1 of each block: rows blk*2, blk*2+1.
    if (w < 2) ln_one_row(blk * 2 + w, lane, h, ln1w, ln1b, A2, crow);
    grid.sync();

    // ---- P3: gemm L2.
    {
        int W = blk * 4 + w;
        int m = W >> 5, n16 = W & 31;
        v4f acc = gemm_k512_1(A2 + m * 8192 + lane * 8,
                              Ew + 262144 + n16 * 8192 + lane * 8);
        int col = n16 * 16 + r;
        float bv = b2[col];
#pragma unroll
        for (int tt = 0; tt < 4; ++tt)
            h[(m * 16 + q * 4 + tt) * 512 + col] = __logf(acc[tt]) + bv;
    }
    grid.sync();

    // ---- P4: LN2.
    if (w < 2) ln_one_row(blk * 2 + w, lane, h, ln2w, ln2b, A3, crow);
    grid.sync();

    // ---- P5: gemm L3 (N=256). Waves 0,1: W3 = blk*2+w (0..1023):
    // m=W3>>4, n16=W3&15. out = log(acc) + crow[row] + b3[col] - ln64.
    if (w < 2) {
        int W3 = blk * 2 + w;
        int m = W3 >> 4, n16 = W3 & 15;
        v4f acc = gemm_k512_1(A3 + m * 8192 + lane * 8,
                              Ew + 524288 + n16 * 8192 + lane * 8);
        int col = n16 * 16 + r;
        float bv = b3[col] - LN64f;
#pragma unroll
        for (int tt = 0; tt < 4; ++tt) {
            int row = m * 16 + q * 4 + tt;
            out[row * 256 + col] = __logf(acc[tt]) + crow[row] + bv;
        }
    }
}

extern "C" void kernel_launch(void* const* d_in, const int* in_sizes, int n_in,
                              void* d_out, int out_size, void* d_ws, size_t ws_size,
                              hipStream_t stream) {
    const float* x    = (const float*)d_in[0];
    const float* w1   = (const float*)d_in[1];
    const float* b1   = (const float*)d_in[2];
    const float* ln1w = (const float*)d_in[3];
    const float* ln1b = (const float*)d_in[4];
    const float* w2   = (const float*)d_in[5];
    const float* b2   = (const float*)d_in[6];
    const float* ln2w = (const float*)d_in[7];
    const float* ln2b = (const float*)d_in[8];
    const float* w3   = (const float*)d_in[9];
    const float* b3   = (const float*)d_in[10];
    float* out = (float*)d_out;

    uint8_t* ws = (uint8_t*)d_ws;
    uint8_t* Ew   = ws;                         // 640 KB (w1|w2|w3 fragments)
    uint8_t* A1   = ws + (1u << 20);            // 512 KB
    uint8_t* A2   = ws + (1u << 20) + 524288;   // 512 KB
    uint8_t* A3   = ws + (2u << 20);            // 512 KB
    float*   h    = (float*)(ws + (2u << 20) + 524288);  // 2 MB
    float*   crow = (float*)(ws + (5u << 20));  // 4 KB

    void* args[] = {&x, &w1, &b1, &ln1w, &ln1b, &w2, &b2, &ln2w, &ln2b,
                    &w3, &b3, &Ew, &A1, &A2, &A3, &h, &crow, &out};
    hipLaunchCooperativeKernel((void*)trop_all, dim3(512), dim3(256),
                               args, 0, stream);
}

// Round 8
// 122.561 us; speedup vs baseline: 3.2671x; 3.2671x over previous
//
#include <hip/hip_runtime.h>
#include <math.h>

// ---------------------------------------------------------------------------
// TropicalMLP, R16: back to the 2-dispatch fused design (R15's cooperative
// grid.sync cost ~60us each -> 310us; reverted). Champion lineage = R11
// (fused <40.3us). Change vs R11: ONE ROW per 256-thread block, 1024 blocks.
//  - 4 independent chains/CU (16 waves/CU same as R11, but de-correlated:
//    one chain's LN (VALU/shuffle) overlaps another's GEMM (MFMA/VMEM)).
//  - barriers sync 4 waves, not 8.
//  - cost: weight stream doubles (640MB L2 aggregate ~ 18.5us floor).
// VGPR discipline (R12 lesson): prefetch depth 2 (bb[2][8]=32 regs), no
// bcur copies, no min-waves clamp; est ~120 VGPR -> 4 blocks/CU.
// Math verbatim R11 (bit-identical): layer1 A=4*exp(x) (+ln4 cancels in LN1
// median); layers2/3 A=64*exp(y-cm) (+ln64-cm cancels in LN2 median /
// subtracted in final epilogue). B=exp(w) in [0.6,1.6], pre-exp'd+permuted
// to MFMA-fragment order by expW_frag. LN: exact order stats, 4 waves/row,
// 2 elem/lane bitonic, jj>=128 rounds via LDS (verified R11 code verbatim).
// ---------------------------------------------------------------------------

typedef float v4f __attribute__((ext_vector_type(4)));

#define LN64f 4.1588830833596715f  // ln(64)

__device__ __forceinline__ int pk4_fp8(float a, float b, float c, float d) {
    int p = __builtin_amdgcn_cvt_pk_fp8_f32(a, b, 0, 0);      // bytes 0,1
    p = __builtin_amdgcn_cvt_pk_fp8_f32(c, d, p, 1);          // bytes 2,3
    return p;
}

// D1: exp + fp8 + fragment reorder. Global 16-col tile S, k-step t (32 k),
// lane l = q*16+r:  Ef[(S*16+t)*512 + l*8 + j] = fp8(exp(W[S*16+r][t*32+q*8+j]))
// S: 0..31 -> w1, 32..63 -> w2, 64..79 -> w3 (contiguous per layer, in bytes).
__global__ __launch_bounds__(256) void expW_frag(const float* __restrict__ w1,
                                                 const float* __restrict__ w2,
                                                 const float* __restrict__ w3,
                                                 uint8_t* __restrict__ Ef) {
    int u = blockIdx.x * 256 + threadIdx.x;          // 0..81919 (320 blocks)
    int lane = u & 63, t = (u >> 6) & 15, S = u >> 10;
    int r = lane & 15, q = lane >> 4;
    const float* w; int tile;
    if (S < 32)      { w = w1; tile = S; }
    else if (S < 64) { w = w2; tile = S - 32; }
    else             { w = w3; tile = S - 64; }
    const float* src = w + (tile * 16 + r) * 512 + t * 32 + q * 8;
    float4 a = *reinterpret_cast<const float4*>(src);
    float4 b = *reinterpret_cast<const float4*>(src + 4);
    int2 o;
    o.x = pk4_fp8(__expf(a.x), __expf(a.y), __expf(a.z), __expf(a.w));
    o.y = pk4_fp8(__expf(b.x), __expf(b.y), __expf(b.z), __expf(b.w));
    *reinterpret_cast<int2*>(Ef + u * 8) = o;
}

// Preload whole A operand (1 row dup'd 16x in the 16-row slot) for all 16
// k-steps: 16 x ds_read_b64, broadcast within each q-group.
__device__ __forceinline__ void load_areg(const uint8_t* Els, int q, long* areg) {
    const uint8_t* ap = Els + q * 8;
#pragma unroll
    for (int t = 0; t < 16; ++t)
        areg[t] = *reinterpret_cast<const long*>(ap + t * 32);
}

// Issue the first 2 k-steps of a layer's B stream (in flight across the
// following barrier / LN — the R8 latency-hiding hoist, depth 2).
template <int NSUB>
__device__ __forceinline__ void prefetchB2(const uint8_t* __restrict__ bp,
                                           int s0, long bb[2][NSUB]) {
#pragma unroll
    for (int p = 0; p < 2; ++p)
#pragma unroll
        for (int s = 0; s < NSUB; ++s)
            bb[p][s] = *reinterpret_cast<const long*>(bp + ((s0 + s) * 16 + p) * 512);
}

// C[16(dup rows) x NSUB*16 cols] over K=512, fp8 MFMA, rolling depth-2 B
// prefetch. MFMA first, then refill the just-consumed slot (no copy temps).
template <int NSUB>
__device__ __forceinline__ void gemm_body2(const uint8_t* __restrict__ bp,
                                           int s0, const long* areg,
                                           long bb[2][NSUB], v4f* acc) {
#pragma unroll
    for (int s = 0; s < NSUB; ++s) acc[s] = (v4f){0.f, 0.f, 0.f, 0.f};
#pragma unroll
    for (int t = 0; t < 16; ++t) {
        long a = areg[t];
#pragma unroll
        for (int s = 0; s < NSUB; ++s)
            acc[s] = __builtin_amdgcn_mfma_f32_16x16x32_fp8_fp8(a, bb[t & 1][s],
                                                                acc[s], 0, 0, 0);
        if (t < 14) {
#pragma unroll
            for (int s = 0; s < NSUB; ++s)
                bb[t & 1][s] =
                    *reinterpret_cast<const long*>(bp + ((s0 + s) * 16 + t + 2) * 512);
        }
    }
}

// In-wave bitonic rounds for stage k: jj = jjhi..2 via shfl (lm = jj/2 lane
// mask), then jj=1 in-lane. 2 elements/lane, e = ebase + {0,1}.
__device__ __forceinline__ void sort_shuf(float& v0, float& v1, int lane,
                                          int ebase, int k, int jjhi) {
#pragma clang loop unroll(disable)
    for (int jj = jjhi; jj >= 2; jj >>= 1) {
        int lm = jj >> 1;
        bool keepmin = (((ebase & k) == 0) == ((lane & lm) == 0));
        float p0 = __shfl_xor(v0, lm);
        float p1 = __shfl_xor(v1, lm);
        v0 = keepmin ? fminf(v0, p0) : fmaxf(v0, p0);
        v1 = keepmin ? fminf(v1, p1) : fmaxf(v1, p1);
    }
    bool up = ((ebase & k) == 0);
    float lo = fminf(v0, v1), hi = fmaxf(v0, v1);
    v0 = up ? lo : hi;
    v1 = up ? hi : lo;
}

// Tropical-LN on the block's single row, 4 waves (W = wave 0..3), 2
// elements/lane: exact order stats via bitonic sort; jj>=128 rounds exchange
// through hb (LDS); relu; subtract rowmax; 64*exp -> fp8 into Els.
// MUST be called by all 4 waves (internal __syncthreads). Verbatim R11.
__device__ __forceinline__ void ln_row4(float* hb,
                                        const float* __restrict__ lw,
                                        const float* __restrict__ lb,
                                        uint8_t* Els_row, float* crow_row,
                                        float* cmx_row,           // [4]
                                        int W, int lane) {
    const int e0 = W * 128 + lane * 2;
    float2 lwv = *reinterpret_cast<const float2*>(lw + e0);
    float2 lbv = *reinterpret_cast<const float2*>(lb + e0);
    float2 hv = *reinterpret_cast<const float2*>(hb + e0);
    float h0 = hv.x, h1 = hv.y, v0 = h0, v1 = h1;

    // Phase A: k = 2..128 (all rounds within a wave).
#pragma clang loop unroll(disable)
    for (int k = 2; k <= 128; k <<= 1)
        sort_shuf(v0, v1, lane, e0, k, (k >> 1) > 64 ? 64 : (k >> 1));

    // Phase B: k = 256. jj=128 exchange via LDS, then in-wave.
    __syncthreads();                           // everyone's initial hb reads done
    *reinterpret_cast<float2*>(hb + e0) = make_float2(v0, v1);
    __syncthreads();
    {
        bool keepmin = (((e0 & 256) == 0) == ((e0 & 128) == 0));
        float2 p = *reinterpret_cast<const float2*>(hb + (e0 ^ 128));
        v0 = keepmin ? fminf(v0, p.x) : fmaxf(v0, p.x);
        v1 = keepmin ? fminf(v1, p.y) : fmaxf(v1, p.y);
    }
    sort_shuf(v0, v1, lane, e0, 256, 64);

    // Phase C: k = 512. jj=256 and jj=128 exchanges, then in-wave.
    __syncthreads();
    *reinterpret_cast<float2*>(hb + e0) = make_float2(v0, v1);
    __syncthreads();
    {
        bool keepmin = ((e0 & 256) == 0);      // ascending final stage
        float2 p = *reinterpret_cast<const float2*>(hb + (e0 ^ 256));
        v0 = keepmin ? fminf(v0, p.x) : fmaxf(v0, p.x);
        v1 = keepmin ? fminf(v1, p.y) : fmaxf(v1, p.y);
    }
    __syncthreads();
    *reinterpret_cast<float2*>(hb + e0) = make_float2(v0, v1);
    __syncthreads();
    {
        bool keepmin = ((e0 & 128) == 0);
        float2 p = *reinterpret_cast<const float2*>(hb + (e0 ^ 128));
        v0 = keepmin ? fminf(v0, p.x) : fmaxf(v0, p.x);
        v1 = keepmin ? fminf(v1, p.y) : fmaxf(v1, p.y);
    }
    sort_shuf(v0, v1, lane, e0, 512, 64);

    // Write-back + order-stat broadcast reads.
    __syncthreads();
    *reinterpret_cast<float2*>(hb + e0) = make_float2(v0, v1);
    __syncthreads();
    float s127 = hb[127], s128 = hb[128], med = hb[255];
    float s383 = hb[383], s384 = hb[384];
    float q25 = s127 + 0.75f * (s128 - s127);
    float q75 = s383 + 0.25f * (s384 - s383);
    float inv = 1.0f / fmaxf(q75 - q25, 1e-6f);

    float y0 = fmaxf((h0 - med) * inv * lwv.x + lbv.x, 0.0f);
    float y1 = fmaxf((h1 - med) * inv * lwv.y + lbv.y, 0.0f);
    float cm = fmaxf(y0, y1);
#pragma unroll
    for (int s = 32; s > 0; s >>= 1) cm = fmaxf(cm, __shfl_xor(cm, s));
    if (lane == 0) cmx_row[W] = cm;
    __syncthreads();
    cm = fmaxf(fmaxf(cmx_row[0], cmx_row[1]), fmaxf(cmx_row[2], cmx_row[3]));

    int p = __builtin_amdgcn_cvt_pk_fp8_f32(64.0f * __expf(y0 - cm),
                                            64.0f * __expf(y1 - cm), 0, 0);
    *reinterpret_cast<ushort*>(Els_row + e0) = (ushort)p;
    if (lane == 0 && W == 0) crow_row[0] = cm;
}

__global__ __launch_bounds__(256) void fused_rows(
    const float* __restrict__ x,
    const float* __restrict__ b1,
    const float* __restrict__ ln1w, const float* __restrict__ ln1b,
    const float* __restrict__ b2,
    const float* __restrict__ ln2w, const float* __restrict__ ln2b,
    const float* __restrict__ b3,
    const uint8_t* __restrict__ Ew,
    float* __restrict__ out)
{
    __shared__ uint8_t Els[512];               // fp8 activations (1 row)
    __shared__ float hbuf[512];                // pre-LN output / sort scratch
    __shared__ float crow[1];                  // row shift (last LN)
    __shared__ float cmx[4];                   // per-wave max partials

    const int tid = threadIdx.x;
    const int lane = tid & 63;
    const int w = tid >> 6;                    // wave id 0..3
    const int r = lane & 15, q = lane >> 4;
    const int blk = blockIdx.x;                // row blk (0..1023)

    const uint8_t* bp1 = Ew + lane * 8;
    const uint8_t* bp2 = bp1 + 262144;
    const uint8_t* bp3 = bp1 + 524288;

    long bb[2][8];
    long bb3[2][4];
    long areg[16];
    v4f acc[8];

    // ---- layer-1 B prefetch in flight during the exp(x) prologue ----
    prefetchB2<8>(bp1, w * 8, bb);

    // ---- phase 0: A1 = fp8(4*exp(x)) for this block's row ----
    // (+ln4 shift cancels in LN1's median subtraction; keeps fp8 normal-range)
    {
        int col = tid * 2;
        float2 a = *reinterpret_cast<const float2*>(x + blk * 512 + col);
        int p = __builtin_amdgcn_cvt_pk_fp8_f32(4.0f * __expf(a.x),
                                                4.0f * __expf(a.y), 0, 0);
        *reinterpret_cast<ushort*>(&Els[col]) = (ushort)p;
    }
    __syncthreads();

    // ===== layer 1: wave w covers cols w*128..w*128+127 (tiles w*8..w*8+7) ====
    load_areg(Els, q, areg);
    gemm_body2<8>(bp1, w * 8, areg, bb, acc);
    {   // epilogue spread over q-groups: lane group q owns subtiles 2q, 2q+1.
        // All 16 C rows identical (A dup'd) -> acc[s][0].
        v4f a0 = (q == 0) ? acc[0] : (q == 1) ? acc[2] : (q == 2) ? acc[4] : acc[6];
        v4f a1 = (q == 0) ? acc[1] : (q == 1) ? acc[3] : (q == 2) ? acc[5] : acc[7];
        int c0 = (w * 8 + 2 * q) * 16 + r, c1 = c0 + 16;
        hbuf[c0] = __logf(a0[0]) + b1[c0];
        hbuf[c1] = __logf(a1[0]) + b1[c1];
    }
    prefetchB2<8>(bp2, w * 8, bb);             // layer-2 B rides over LN1
    __syncthreads();
    ln_row4(hbuf, ln1w, ln1b, Els, crow, cmx, w, lane);
    __syncthreads();

    // ===== layer 2 (uniform ln64 - cm1 shift absorbed by LN2's median) =====
    load_areg(Els, q, areg);
    gemm_body2<8>(bp2, w * 8, areg, bb, acc);
    {
        v4f a0 = (q == 0) ? acc[0] : (q == 1) ? acc[2] : (q == 2) ? acc[4] : acc[6];
        v4f a1 = (q == 0) ? acc[1] : (q == 1) ? acc[3] : (q == 2) ? acc[5] : acc[7];
        int c0 = (w * 8 + 2 * q) * 16 + r, c1 = c0 + 16;
        hbuf[c0] = __logf(a0[0]) + b2[c0];
        hbuf[c1] = __logf(a1[0]) + b2[c1];
    }
    prefetchB2<4>(bp3, w * 4, bb3);            // layer-3 B rides over LN2
    __syncthreads();
    ln_row4(hbuf, ln2w, ln2b, Els, crow, cmx, w, lane);
    __syncthreads();

    // ===== layer 3 (N=256, tiles w*4..w*4+3): out = log(acc)+cm2-ln64+b3 =====
    load_areg(Els, q, areg);
    gemm_body2<4>(bp3, w * 4, areg, bb3, acc);
    {
        v4f av = (q == 0) ? acc[0] : (q == 1) ? acc[1] : (q == 2) ? acc[2] : acc[3];
        int col = (w * 4 + q) * 16 + r;
        out[blk * 256 + col] = __logf(av[0]) + crow[0] + b3[col] - LN64f;
    }
}

extern "C" void kernel_launch(void* const* d_in, const int* in_sizes, int n_in,
                              void* d_out, int out_size, void* d_ws, size_t ws_size,
                              hipStream_t stream) {
    const float* x    = (const float*)d_in[0];
    const float* w1   = (const float*)d_in[1];
    const float* b1   = (const float*)d_in[2];
    const float* ln1w = (const float*)d_in[3];
    const float* ln1b = (const float*)d_in[4];
    const float* w2   = (const float*)d_in[5];
    const float* b2   = (const float*)d_in[6];
    const float* ln2w = (const float*)d_in[7];
    const float* ln2b = (const float*)d_in[8];
    const float* w3   = (const float*)d_in[9];
    const float* b3   = (const float*)d_in[10];
    float* out = (float*)d_out;

    uint8_t* Ew = (uint8_t*)d_ws;              // 655360 B fp8 = 640 KB

    expW_frag<<<320, 256, 0, stream>>>(w1, w2, w3, Ew);
    fused_rows<<<1024, 256, 0, stream>>>(x, b1, ln1w, ln1b, b2, ln2w, ln2b,
                                         b3, Ew, out);
}